// Round 1
// baseline (6341.943 us; speedup 1.0000x reference)
//
#include <hip/hip_runtime.h>
#include <math.h>

#define BSZ 4096        // B*S
#define HDIM 1024
#define IDIM 4096
#define NEGF (-1000000000.0f)

__device__ inline float wredSum(float v){
  #pragma unroll
  for (int off = 32; off; off >>= 1) v += __shfl_xor(v, off);
  return v;
}
__device__ inline float wredMax(float v){
  #pragma unroll
  for (int off = 32; off; off >>= 1) v = fmaxf(v, __shfl_xor(v, off));
  return v;
}

// ---------------- router: scores, argmax, softmax weight, copy hidden -> out ----
__global__ __launch_bounds__(256) void router_kernel(
    const float* __restrict__ hidden, const float* __restrict__ ek,
    float* __restrict__ out, float* __restrict__ act0, float* __restrict__ act1,
    float* __restrict__ g0, float* __restrict__ g1)
{
  const int lane = threadIdx.x & 63, wid = threadIdx.x >> 6;
  const int row = blockIdx.x * 4 + wid;
  const float* hr = hidden + (size_t)row * HDIM;
  float4 xv[4];
  float s0 = 0.f, s1 = 0.f, s2 = 0.f, s3 = 0.f;
  #pragma unroll
  for (int tt = 0; tt < 4; ++tt){
    const int o = tt * 256 + lane * 4;
    xv[tt] = *(const float4*)&hr[o];
    const float4 e0 = *(const float4*)&ek[0 * HDIM + o];
    const float4 e1 = *(const float4*)&ek[1 * HDIM + o];
    const float4 e2 = *(const float4*)&ek[2 * HDIM + o];
    const float4 e3 = *(const float4*)&ek[3 * HDIM + o];
    s0 += xv[tt].x * e0.x + xv[tt].y * e0.y + xv[tt].z * e0.z + xv[tt].w * e0.w;
    s1 += xv[tt].x * e1.x + xv[tt].y * e1.y + xv[tt].z * e1.z + xv[tt].w * e1.w;
    s2 += xv[tt].x * e2.x + xv[tt].y * e2.y + xv[tt].z * e2.z + xv[tt].w * e2.w;
    s3 += xv[tt].x * e3.x + xv[tt].y * e3.y + xv[tt].z * e3.z + xv[tt].w * e3.w;
  }
  s0 = wredSum(s0); s1 = wredSum(s1); s2 = wredSum(s2); s3 = wredSum(s3);
  int ch = 0; float mx = s0;
  if (s1 > mx){ mx = s1; ch = 1; }
  if (s2 > mx){ mx = s2; ch = 2; }
  if (s3 > mx){ mx = s3; ch = 3; }
  const float den = expf(s0 - mx) + expf(s1 - mx) + expf(s2 - mx) + expf(s3 - mx);
  const float wsel = 1.0f / den;
  if (lane == 0){
    const float a0 = (float)(ch & 1), a1 = (float)((ch >> 1) & 1);
    act0[row] = a0; act1[row] = a1; g0[row] = a0 * wsel; g1[row] = a1 * wsel;
  }
  float* orow = out + (size_t)row * HDIM;
  #pragma unroll
  for (int tt = 0; tt < 4; ++tt) *(float4*)&orow[tt * 256 + lane * 4] = xv[tt];
}

// ---------------- rmsnorm (optionally x = src + act*ek, writes x and hn) -------
template<bool ADD_EK>
__global__ __launch_bounds__(256) void rms_kernel(
    const float* __restrict__ src, const float* __restrict__ ekrow,
    const float* __restrict__ act, const float* __restrict__ g,
    float* __restrict__ xout, float* __restrict__ hn)
{
  const int row = blockIdx.x;
  const int t = threadIdx.x;
  const int lane = t & 63, wid = t >> 6;
  const float* sr = src + (size_t)row * HDIM;
  float4 xv = *(const float4*)&sr[t * 4];
  if constexpr (ADD_EK){
    const float a = act[row];
    const float4 e = *(const float4*)&ekrow[t * 4];
    xv.x = fmaf(a, e.x, xv.x); xv.y = fmaf(a, e.y, xv.y);
    xv.z = fmaf(a, e.z, xv.z); xv.w = fmaf(a, e.w, xv.w);
  }
  float ss = xv.x*xv.x + xv.y*xv.y + xv.z*xv.z + xv.w*xv.w;
  ss = wredSum(ss);
  __shared__ float red[4];
  if (lane == 0) red[wid] = ss;
  __syncthreads();
  const float tot = red[0] + red[1] + red[2] + red[3];
  const float inv = rsqrtf(tot * (1.0f / HDIM) + 1e-6f);
  if constexpr (ADD_EK) *(float4*)&xout[(size_t)row * HDIM + t * 4] = xv;
  const float4 gg = *(const float4*)&g[t * 4];
  float4 h;
  h.x = xv.x * inv * gg.x; h.y = xv.y * inv * gg.y;
  h.z = xv.z * inv * gg.z; h.w = xv.w * inv * gg.w;
  *(float4*)&hn[(size_t)row * HDIM + t * 4] = h;
}

// ---------------- RoPE in-place on q or k --------------------------------------
__global__ __launch_bounds__(256) void rope_kernel(
    float* __restrict__ t_qk, const int* __restrict__ pos_ids)
{
  const int t = threadIdx.x;
  const int u = blockIdx.x * 8 + (t >> 5);
  const int j = t & 31;
  const int row = u >> 4;     // b*S+s
  const int head = u & 15;
  const float pos = (float)pos_ids[row];
  const float inv = powf(10000.0f, -(float)j * (1.0f / 32.0f));
  const float ang = pos * inv;
  float sn, cs;
  sincosf(ang, &sn, &cs);
  float* p = t_qk + (size_t)row * HDIM + head * 64;
  const float a = p[j], b = p[j + 32];
  p[j]      = a * cs - b * sn;
  p[j + 32] = b * cs + a * sn;
}

// ---------------- tiled fp32 GEMM, epilogue modes ------------------------------
// MODE 0: C = A@W
// MODE 1: C = res + A@W
// MODE 2: C += gate[row] * (res + A@W)     (C = d_out accumulator)
template<int MODE>
__global__ __launch_bounds__(256) void gemm_f32(
    const float* __restrict__ A, const float* __restrict__ W,
    float* __restrict__ C, const float* __restrict__ res,
    const float* __restrict__ gate, int M, int N, int K)
{
  __shared__ float As[16][68];
  __shared__ float Bs[16][64];
  const int tid = threadIdx.x;
  const int bm = blockIdx.y * 64, bn = blockIdx.x * 64;
  const int tx = tid & 15, ty = tid >> 4;
  const int mA = tid >> 2, kA = (tid & 3) * 4;
  const int kB = tid >> 4, nB = (tid & 15) * 4;
  float acc[4][4] = {};
  for (int k0 = 0; k0 < K; k0 += 16){
    const float4 a  = *(const float4*)&A[(size_t)(bm + mA) * K + k0 + kA];
    const float4 bb = *(const float4*)&W[(size_t)(k0 + kB) * N + bn + nB];
    __syncthreads();
    As[kA + 0][mA] = a.x; As[kA + 1][mA] = a.y;
    As[kA + 2][mA] = a.z; As[kA + 3][mA] = a.w;
    *(float4*)&Bs[kB][nB] = bb;
    __syncthreads();
    #pragma unroll
    for (int kk = 0; kk < 16; ++kk){
      const float4 av = *(const float4*)&As[kk][ty * 4];
      const float4 bv = *(const float4*)&Bs[kk][tx * 4];
      const float a4[4] = {av.x, av.y, av.z, av.w};
      const float b4[4] = {bv.x, bv.y, bv.z, bv.w};
      #pragma unroll
      for (int i = 0; i < 4; ++i)
        #pragma unroll
        for (int j = 0; j < 4; ++j)
          acc[i][j] = fmaf(a4[i], b4[j], acc[i][j]);
    }
  }
  const int row = bm + ty * 4, col = bn + tx * 4;
  #pragma unroll
  for (int i = 0; i < 4; ++i){
    float4 r4 = make_float4(acc[i][0], acc[i][1], acc[i][2], acc[i][3]);
    if constexpr (MODE == 1){
      const float4 rr = *(const float4*)&res[(size_t)(row + i) * N + col];
      r4.x += rr.x; r4.y += rr.y; r4.z += rr.z; r4.w += rr.w;
      *(float4*)&C[(size_t)(row + i) * N + col] = r4;
    } else if constexpr (MODE == 2){
      const float gt = gate[row + i];
      const float4 rr = *(const float4*)&res[(size_t)(row + i) * N + col];
      float4 o4 = *(float4*)&C[(size_t)(row + i) * N + col];
      o4.x += gt * (rr.x + r4.x); o4.y += gt * (rr.y + r4.y);
      o4.z += gt * (rr.z + r4.z); o4.w += gt * (rr.w + r4.w);
      *(float4*)&C[(size_t)(row + i) * N + col] = o4;
    } else {
      *(float4*)&C[(size_t)(row + i) * N + col] = r4;
    }
  }
}

// ---------------- fused gate-up GEMM: P = silu(A@Wg) * (A@Wu) ------------------
__global__ __launch_bounds__(256) void gemm_gu(
    const float* __restrict__ A, const float* __restrict__ Wgp,
    const float* __restrict__ Wup, float* __restrict__ P, int M, int N, int K)
{
  __shared__ float As[16][68];
  __shared__ float Gs[16][64];
  __shared__ float Us[16][64];
  const int tid = threadIdx.x;
  const int bm = blockIdx.y * 64, bn = blockIdx.x * 64;
  const int tx = tid & 15, ty = tid >> 4;
  const int mA = tid >> 2, kA = (tid & 3) * 4;
  const int kB = tid >> 4, nB = (tid & 15) * 4;
  float accG[4][4] = {};
  float accU[4][4] = {};
  for (int k0 = 0; k0 < K; k0 += 16){
    const float4 a  = *(const float4*)&A[(size_t)(bm + mA) * K + k0 + kA];
    const float4 gg = *(const float4*)&Wgp[(size_t)(k0 + kB) * N + bn + nB];
    const float4 uu = *(const float4*)&Wup[(size_t)(k0 + kB) * N + bn + nB];
    __syncthreads();
    As[kA + 0][mA] = a.x; As[kA + 1][mA] = a.y;
    As[kA + 2][mA] = a.z; As[kA + 3][mA] = a.w;
    *(float4*)&Gs[kB][nB] = gg;
    *(float4*)&Us[kB][nB] = uu;
    __syncthreads();
    #pragma unroll
    for (int kk = 0; kk < 16; ++kk){
      const float4 av = *(const float4*)&As[kk][ty * 4];
      const float4 gv = *(const float4*)&Gs[kk][tx * 4];
      const float4 uv = *(const float4*)&Us[kk][tx * 4];
      const float a4[4] = {av.x, av.y, av.z, av.w};
      const float g4[4] = {gv.x, gv.y, gv.z, gv.w};
      const float u4[4] = {uv.x, uv.y, uv.z, uv.w};
      #pragma unroll
      for (int i = 0; i < 4; ++i)
        #pragma unroll
        for (int j = 0; j < 4; ++j){
          accG[i][j] = fmaf(a4[i], g4[j], accG[i][j]);
          accU[i][j] = fmaf(a4[i], u4[j], accU[i][j]);
        }
    }
  }
  const int row = bm + ty * 4, col = bn + tx * 4;
  #pragma unroll
  for (int i = 0; i < 4; ++i){
    float4 r4;
    float* rp = &r4.x;
    #pragma unroll
    for (int j = 0; j < 4; ++j){
      const float g = accG[i][j];
      const float sig = 1.0f / (1.0f + expf(-g));
      rp[j] = g * sig * accU[i][j];
    }
    *(float4*)&P[(size_t)(row + i) * N + col] = r4;
  }
}

// ---------------- flash attention: 1 wave per query row, 64-key chunks ---------
__global__ __launch_bounds__(256) void attn_kernel(
    const float* __restrict__ q, const float* __restrict__ k,
    const float* __restrict__ v, const float* __restrict__ act,
    float* __restrict__ o)
{
  __shared__ float K_s[64][65];
  __shared__ float V_s[64][64];
  const int tid = threadIdx.x;
  const int lane = tid & 63, w = tid >> 6;
  const int b = blockIdx.z, h = blockIdx.y;
  const int r0 = blockIdx.x * 4;
  const int r = r0 + w;
  const size_t qoff = ((size_t)(b * 1024 + r)) * HDIM + h * 64;
  const float qreg = q[qoff + lane];
  float m = -INFINITY, l = 0.f, oacc = 0.f;
  const int nchunks = ((r0 + 3) >> 6) + 1;
  const int jl = tid >> 2, d0 = (tid & 3) * 16;
  for (int c = 0; c < nchunks; ++c){
    const int j0 = c << 6;
    __syncthreads();
    {
      const size_t kvoff = ((size_t)(b * 1024 + j0 + jl)) * HDIM + h * 64 + d0;
      #pragma unroll
      for (int tl = 0; tl < 4; ++tl){
        const float4 k4 = *(const float4*)&k[kvoff + tl * 4];
        K_s[jl][d0 + tl * 4 + 0] = k4.x;
        K_s[jl][d0 + tl * 4 + 1] = k4.y;
        K_s[jl][d0 + tl * 4 + 2] = k4.z;
        K_s[jl][d0 + tl * 4 + 3] = k4.w;
        const float4 v4 = *(const float4*)&v[kvoff + tl * 4];
        *(float4*)&V_s[jl][d0 + tl * 4] = v4;
      }
    }
    __syncthreads();
    if (j0 <= r){
      const int key = j0 + lane;
      float s = 0.f;
      #pragma unroll
      for (int dd = 0; dd < 64; ++dd)
        s = fmaf(__shfl(qreg, dd), K_s[lane][dd], s);
      s *= 0.125f;
      if (key > r) s += NEGF;
      s += (1.0f - act[b * 1024 + key]) * NEGF;
      const float cmax = wredMax(s);
      const float mn = fmaxf(m, cmax);
      const float sc = expf(m - mn);
      const float p = expf(s - mn);
      l = l * sc + wredSum(p);
      oacc *= sc;
      #pragma unroll
      for (int j = 0; j < 64; ++j)
        oacc = fmaf(__shfl(p, j), V_s[j][lane], oacc);
      m = mn;
    }
  }
  o[qoff + lane] = oacc / l;
}

extern "C" void kernel_launch(void* const* d_in, const int* in_sizes, int n_in,
                              void* d_out, int out_size, void* d_ws, size_t ws_size,
                              hipStream_t stream)
{
  (void)in_sizes; (void)n_in; (void)out_size;
  const float* hidden = (const float*)d_in[0];
  const int*   posids = (const int*)d_in[2];
  const float* ek     = (const float*)d_in[3];
  const float* Wq  = (const float*)d_in[4];
  const float* Wk  = (const float*)d_in[5];
  const float* Wv  = (const float*)d_in[6];
  const float* Wo  = (const float*)d_in[7];
  const float* Wg  = (const float*)d_in[8];
  const float* Wu  = (const float*)d_in[9];
  const float* Wd  = (const float*)d_in[10];
  const float* ln1 = (const float*)d_in[11];
  const float* ln2 = (const float*)d_in[12];
  float* out = (float*)d_out;
  float* wsf = (float*)d_ws;

  const size_t SZ = (size_t)BSZ * HDIM;          // 4,194,304 floats
  float* bufX = wsf;                              // x
  float* bufA = wsf + SZ;                         // hn, then attention o
  float* bufB = wsf + 2 * SZ;                     // q, then x2
  float* bufC = wsf + 3 * SZ;                     // k, then h2
  float* bufD = wsf + 4 * SZ;                     // v
  float* bufP = wsf + 5 * SZ;                     // silu(g)*u  (BSZ x IDIM)
  float* act0 = wsf + 5 * SZ + (size_t)BSZ * IDIM;
  float* act1 = act0 + BSZ;
  float* g0   = act1 + BSZ;
  float* g1   = g0 + BSZ;
  const size_t needed = (5 * SZ + (size_t)BSZ * IDIM + 4 * BSZ) * sizeof(float);
  if (ws_size < needed) return;   // loud failure instead of corruption

  router_kernel<<<BSZ / 4, 256, 0, stream>>>(hidden, ek, out, act0, act1, g0, g1);

  for (int d = 0; d < 2; ++d){
    const float* act  = d ? act1 : act0;
    const float* gate = d ? g1 : g0;
    const float* ekrow = ek + (size_t)(1 << d) * HDIM;
    const float* wq = Wq + (size_t)d * HDIM * HDIM;
    const float* wk = Wk + (size_t)d * HDIM * HDIM;
    const float* wv = Wv + (size_t)d * HDIM * HDIM;
    const float* wo = Wo + (size_t)d * HDIM * HDIM;
    const float* wg = Wg + (size_t)d * HDIM * IDIM;
    const float* wu = Wu + (size_t)d * HDIM * IDIM;
    const float* wd = Wd + (size_t)d * IDIM * HDIM;

    rms_kernel<true><<<BSZ, 256, 0, stream>>>(out, ekrow, act, ln1 + (size_t)d * HDIM, bufX, bufA);
    gemm_f32<0><<<dim3(HDIM / 64, BSZ / 64), 256, 0, stream>>>(bufA, wq, bufB, nullptr, nullptr, BSZ, HDIM, HDIM);
    gemm_f32<0><<<dim3(HDIM / 64, BSZ / 64), 256, 0, stream>>>(bufA, wk, bufC, nullptr, nullptr, BSZ, HDIM, HDIM);
    gemm_f32<0><<<dim3(HDIM / 64, BSZ / 64), 256, 0, stream>>>(bufA, wv, bufD, nullptr, nullptr, BSZ, HDIM, HDIM);
    rope_kernel<<<BSZ * 16 / 8, 256, 0, stream>>>(bufB, posids);
    rope_kernel<<<BSZ * 16 / 8, 256, 0, stream>>>(bufC, posids);
    attn_kernel<<<dim3(1024 / 4, 16, 4), 256, 0, stream>>>(bufB, bufC, bufD, act, bufA);
    gemm_f32<1><<<dim3(HDIM / 64, BSZ / 64), 256, 0, stream>>>(bufA, wo, bufB, bufX, nullptr, BSZ, HDIM, HDIM);
    rms_kernel<false><<<BSZ, 256, 0, stream>>>(bufB, nullptr, nullptr, ln2 + (size_t)d * HDIM, nullptr, bufC);
    gemm_gu<<<dim3(IDIM / 64, BSZ / 64), 256, 0, stream>>>(bufC, wg, wu, bufP, BSZ, IDIM, HDIM);
    gemm_f32<2><<<dim3(HDIM / 64, BSZ / 64), 256, 0, stream>>>(bufP, wd, out, bufB, gate, BSZ, HDIM, IDIM);
  }
}

// Round 4
// 945.109 us; speedup vs baseline: 6.7103x; 6.7103x over previous
//
#include <hip/hip_runtime.h>
#include <math.h>

#define BSZ 4096        // B*S
#define HDIM 1024
#define IDIM 4096
#define NEGF (-1000000000.0f)

typedef __attribute__((ext_vector_type(8))) short bf16x8s;   // 8 bf16 in 4 VGPR
typedef __attribute__((ext_vector_type(4))) float f32x4;
typedef __attribute__((ext_vector_type(2))) unsigned int u32x2;
typedef __attribute__((ext_vector_type(4))) unsigned int u32x4;

#define GLDS(src, dst) __builtin_amdgcn_global_load_lds( \
    (const __attribute__((address_space(1))) void*)(src), \
    (__attribute__((address_space(3))) void*)(dst), 16, 0, 0)

__device__ inline unsigned short f2bf(float f){
  __bf16 h = (__bf16)f;
  return __builtin_bit_cast(unsigned short, h);
}
__device__ inline float bf2f(unsigned short u){
  unsigned x = ((unsigned)u) << 16;
  return __builtin_bit_cast(float, x);
}

__device__ inline float wredSum(float v){
  #pragma unroll
  for (int off = 32; off; off >>= 1) v += __shfl_xor(v, off);
  return v;
}

// ---------------- router: scores, argmax, softmax weight, copy hidden -> out ----
__global__ __launch_bounds__(256) void router_kernel(
    const float* __restrict__ hidden, const float* __restrict__ ek,
    float* __restrict__ out, float* __restrict__ act0, float* __restrict__ act1,
    float* __restrict__ g0, float* __restrict__ g1)
{
  const int lane = threadIdx.x & 63, wid = threadIdx.x >> 6;
  const int row = blockIdx.x * 4 + wid;
  const float* hr = hidden + (size_t)row * HDIM;
  float4 xv[4];
  float s0 = 0.f, s1 = 0.f, s2 = 0.f, s3 = 0.f;
  #pragma unroll
  for (int tt = 0; tt < 4; ++tt){
    const int o = tt * 256 + lane * 4;
    xv[tt] = *(const float4*)&hr[o];
    const float4 e0 = *(const float4*)&ek[0 * HDIM + o];
    const float4 e1 = *(const float4*)&ek[1 * HDIM + o];
    const float4 e2 = *(const float4*)&ek[2 * HDIM + o];
    const float4 e3 = *(const float4*)&ek[3 * HDIM + o];
    s0 += xv[tt].x * e0.x + xv[tt].y * e0.y + xv[tt].z * e0.z + xv[tt].w * e0.w;
    s1 += xv[tt].x * e1.x + xv[tt].y * e1.y + xv[tt].z * e1.z + xv[tt].w * e1.w;
    s2 += xv[tt].x * e2.x + xv[tt].y * e2.y + xv[tt].z * e2.z + xv[tt].w * e2.w;
    s3 += xv[tt].x * e3.x + xv[tt].y * e3.y + xv[tt].z * e3.z + xv[tt].w * e3.w;
  }
  s0 = wredSum(s0); s1 = wredSum(s1); s2 = wredSum(s2); s3 = wredSum(s3);
  int ch = 0; float mx = s0;
  if (s1 > mx){ mx = s1; ch = 1; }
  if (s2 > mx){ mx = s2; ch = 2; }
  if (s3 > mx){ mx = s3; ch = 3; }
  const float den = expf(s0 - mx) + expf(s1 - mx) + expf(s2 - mx) + expf(s3 - mx);
  const float wsel = 1.0f / den;
  if (lane == 0){
    const float a0 = (float)(ch & 1), a1 = (float)((ch >> 1) & 1);
    act0[row] = a0; act1[row] = a1; g0[row] = a0 * wsel; g1[row] = a1 * wsel;
  }
  float* orow = out + (size_t)row * HDIM;
  #pragma unroll
  for (int tt = 0; tt < 4; ++tt) *(float4*)&orow[tt * 256 + lane * 4] = xv[tt];
}

// ---------------- weight transpose+convert: fp32 [K][N] -> bf16 [N][K] ---------
__global__ __launch_bounds__(256) void wtr_kernel(
    const float* __restrict__ src, unsigned short* __restrict__ dst, int K, int N)
{
  __shared__ float T[64][65];
  const int tid = threadIdx.x;
  const int k0 = blockIdx.y * 64, n0 = blockIdx.x * 64;
  const int tx = tid & 15, ty = tid >> 4;
  #pragma unroll
  for (int i = 0; i < 4; ++i){
    const float4 v = *(const float4*)&src[(size_t)(k0 + ty + i*16) * N + n0 + tx*4];
    T[ty + i*16][tx*4 + 0] = v.x;
    T[ty + i*16][tx*4 + 1] = v.y;
    T[ty + i*16][tx*4 + 2] = v.z;
    T[ty + i*16][tx*4 + 3] = v.w;
  }
  __syncthreads();
  #pragma unroll
  for (int i = 0; i < 4; ++i){
    ushort4 u;
    u.x = f2bf(T[tx*4 + 0][ty + i*16]);
    u.y = f2bf(T[tx*4 + 1][ty + i*16]);
    u.z = f2bf(T[tx*4 + 2][ty + i*16]);
    u.w = f2bf(T[tx*4 + 3][ty + i*16]);
    *(ushort4*)&dst[(size_t)(n0 + ty + i*16) * K + k0 + tx*4] = u;
  }
}

// ---------------- rmsnorm: optionally x = src + act*ek; writes x f32, hn bf16 ---
template<bool ADD_EK>
__global__ __launch_bounds__(256) void rms_kernel(
    const float* __restrict__ src, const float* __restrict__ ekrow,
    const float* __restrict__ act, const float* __restrict__ g,
    float* __restrict__ xout, unsigned short* __restrict__ hn)
{
  const int row = blockIdx.x;
  const int t = threadIdx.x;
  const int lane = t & 63, wid = t >> 6;
  const float* sr = src + (size_t)row * HDIM;
  float4 xv = *(const float4*)&sr[t * 4];
  if constexpr (ADD_EK){
    const float a = act[row];
    const float4 e = *(const float4*)&ekrow[t * 4];
    xv.x = fmaf(a, e.x, xv.x); xv.y = fmaf(a, e.y, xv.y);
    xv.z = fmaf(a, e.z, xv.z); xv.w = fmaf(a, e.w, xv.w);
  }
  float ss = xv.x*xv.x + xv.y*xv.y + xv.z*xv.z + xv.w*xv.w;
  ss = wredSum(ss);
  __shared__ float red[4];
  if (lane == 0) red[wid] = ss;
  __syncthreads();
  const float tot = red[0] + red[1] + red[2] + red[3];
  const float inv = rsqrtf(tot * (1.0f / HDIM) + 1e-6f);
  if constexpr (ADD_EK) *(float4*)&xout[(size_t)row * HDIM + t * 4] = xv;
  const float4 gg = *(const float4*)&g[t * 4];
  ushort4 hu;
  hu.x = f2bf(xv.x * inv * gg.x); hu.y = f2bf(xv.y * inv * gg.y);
  hu.z = f2bf(xv.z * inv * gg.z); hu.w = f2bf(xv.w * inv * gg.w);
  *(ushort4*)&hn[(size_t)row * HDIM + t * 4] = hu;
}

// ---------------- RoPE in-place on bf16 q or k ---------------------------------
__global__ __launch_bounds__(256) void rope_bf16(
    unsigned short* __restrict__ t_qk, const int* __restrict__ pos_ids)
{
  const int t = threadIdx.x;
  const int u = blockIdx.x * 8 + (t >> 5);
  const int j = t & 31;
  const int row = u >> 4;
  const int head = u & 15;
  const float pos = (float)pos_ids[row];
  const float inv = powf(10000.0f, -(float)j * (1.0f / 32.0f));
  float sn, cs;
  sincosf(pos * inv, &sn, &cs);
  unsigned short* p = t_qk + (size_t)row * HDIM + head * 64;
  const float a = bf2f(p[j]), b = bf2f(p[j + 32]);
  p[j]      = f2bf(a * cs - b * sn);
  p[j + 32] = f2bf(b * cs + a * sn);
}

// ---------------- bf16 MFMA GEMM, m97-structure (linear LDS) -------------------
// A bf16 [M][K] row-major, Bt bf16 [N][K] row-major (pre-transposed weights).
// 128x128 tile, BK=32, 4 waves (64x64 each), dbuf LDS via global_load_lds w=16.
// EPI 0: Cb = bf16(acc)
// EPI 1: Cf = res + acc                      (fp32 out)
// EPI 2: Cb = bf16( silu(Cb_old) * acc )     (in-place gate*up)
// EPI 3: outp += gate[row] * (res + acc)     (fp32 accumulate into d_out)
template<int EPI>
__global__ __launch_bounds__(256) void gemm_bf16(
    const unsigned short* __restrict__ A, const unsigned short* __restrict__ Bt,
    int N, int K,
    unsigned short* __restrict__ Cb, float* __restrict__ Cf,
    const float* __restrict__ res, const float* __restrict__ gate,
    float* __restrict__ outp)
{
  __shared__ __align__(16) unsigned short As[8192];   // 2 bufs x 128x32
  __shared__ __align__(16) unsigned short Bs[8192];
  const int tid = threadIdx.x;
  const int lane = tid & 63, w = tid >> 6;
  const int g = lane >> 4;
  const int bm = blockIdx.y * 128, bn = blockIdx.x * 128;
  const int wr = w >> 1, wc = w & 1;

  // staging: thread covers 2 chunks of 16B per tile (linear layout)
  const int rA0 = tid >> 2, rA1 = rA0 + 64;
  const int c0 = (tid & 3) * 8;
  const unsigned short* gA0 = A  + (size_t)(bm + rA0) * K + c0;
  const unsigned short* gA1 = A  + (size_t)(bm + rA1) * K + c0;
  const unsigned short* gB0 = Bt + (size_t)(bn + rA0) * K + c0;
  const unsigned short* gB1 = Bt + (size_t)(bn + rA1) * K + c0;
  char* ldsA = (char*)As + w * 1024;
  char* ldsB = (char*)Bs + w * 1024;

  int aoff[4], boff[4];
  #pragma unroll
  for (int i = 0; i < 4; ++i){
    const int ra = wr*64 + i*16 + (lane & 15);
    aoff[i] = ra*64 + g*16;
    const int rb = wc*64 + i*16 + (lane & 15);
    boff[i] = rb*64 + g*16;
  }

  f32x4 acc[4][4];
  #pragma unroll
  for (int i = 0; i < 4; ++i)
    #pragma unroll
    for (int j = 0; j < 4; ++j){ f32x4 z = {0.f,0.f,0.f,0.f}; acc[i][j] = z; }

  // prologue: stage tile 0 into buf 0
  GLDS(gA0, ldsA);        GLDS(gA1, ldsA + 4096);
  GLDS(gB0, ldsB);        GLDS(gB1, ldsB + 4096);
  gA0 += 32; gA1 += 32; gB0 += 32; gB1 += 32;
  __syncthreads();

  const int nk = K >> 5;
  for (int kt = 0; kt < nk; ++kt){
    const int cur = kt & 1;
    if (kt + 1 < nk){
      char* dA = ldsA + ((cur ^ 1) ? 8192 : 0);
      char* dB = ldsB + ((cur ^ 1) ? 8192 : 0);
      GLDS(gA0, dA); GLDS(gA1, dA + 4096);
      GLDS(gB0, dB); GLDS(gB1, dB + 4096);
      gA0 += 32; gA1 += 32; gB0 += 32; gB1 += 32;
    }
    const char* ta = (const char*)As + cur * 8192;
    const char* tb = (const char*)Bs + cur * 8192;
    bf16x8s af[4], bfr[4];
    #pragma unroll
    for (int i = 0; i < 4; ++i){
      af[i]  = *(const bf16x8s*)(ta + aoff[i]);
      bfr[i] = *(const bf16x8s*)(tb + boff[i]);
    }
    #pragma unroll
    for (int i = 0; i < 4; ++i)
      #pragma unroll
      for (int j = 0; j < 4; ++j)
        acc[i][j] = __builtin_amdgcn_mfma_f32_16x16x32_bf16(af[i], bfr[j], acc[i][j], 0, 0, 0);
    __syncthreads();
  }

  const int colb = bn + wc*64 + (lane & 15);
  const int rowb = bm + wr*64 + g*4;
  #pragma unroll
  for (int i = 0; i < 4; ++i){
    #pragma unroll
    for (int j = 0; j < 4; ++j){
      #pragma unroll
      for (int r = 0; r < 4; ++r){
        const int gr = rowb + i*16 + r;
        const int gc = colb + j*16;
        const size_t idx = (size_t)gr * N + gc;
        const float vacc = acc[i][j][r];
        if constexpr (EPI == 0){
          Cb[idx] = f2bf(vacc);
        } else if constexpr (EPI == 1){
          Cf[idx] = res[idx] + vacc;
        } else if constexpr (EPI == 2){
          const float gv = bf2f(Cb[idx]);
          const float s = gv / (1.0f + expf(-gv));
          Cb[idx] = f2bf(s * vacc);
        } else {
          outp[idx] += gate[gr] * (res[idx] + vacc);
        }
      }
    }
  }
}

// ---------------- MFMA flash attention (16x16x32 intrinsic ONLY) ---------------
// Block: (qt, h, b): 64 q rows, 4 waves x 16 rows. K/V chunks of 64 keys.
// QK^T swapped: S^T = mfma(K-frag, Q-frag) -> lane holds P[q=lane&15][key=g*4+r].
// PV: O = mfma(P-frag, V-frag) with K=32; P-frag words gathered by shfl from the
// lane-local softmax registers; V-frag read from reg-transposed V_t[dd][key+pad72].
__global__ __launch_bounds__(256) void attn_mfma(
    const unsigned short* __restrict__ q, const unsigned short* __restrict__ k,
    const unsigned short* __restrict__ v, const float* __restrict__ act,
    unsigned short* __restrict__ o)
{
  __shared__ __align__(16) unsigned short K_s[4096];      // [64 key][64 d] linear
  __shared__ __align__(16) unsigned short V_t[64 * 72];   // [64 dd][72 key-pad]
  __shared__ float act_s[64];
  const int tid = threadIdx.x;
  const int lane = tid & 63, w = tid >> 6;
  const int g = lane >> 4;
  const int b = blockIdx.z, h = blockIdx.y, qt = blockIdx.x;
  const int qw = qt * 64 + w * 16;
  const int qglob = qw + (lane & 15);

  // Q fragments (reused across all chunks)
  bf16x8s qa[2];
  {
    const size_t qrow = (size_t)(b * 1024 + qglob) * HDIM + h * 64;
    qa[0] = *(const bf16x8s*)&q[qrow + g * 8];
    qa[1] = *(const bf16x8s*)&q[qrow + 32 + g * 8];
  }

  f32x4 oacc[4];
  #pragma unroll
  for (int n = 0; n < 4; ++n){ f32x4 z = {0.f,0.f,0.f,0.f}; oacc[n] = z; }
  float m_r = -3.0e38f, l_r = 0.f;

  // V transpose staging indices: thread covers keys key0..+3, dds dd0..+3
  const int key0 = (tid >> 4) * 4;
  const int dd0  = (tid & 15) * 4;
  const int nch = qt + 1;

  for (int c = 0; c < nch; ++c){
    const int ck0 = c * 64;
    // ---- stage K (8KB, linear via global_load_lds) ----
    #pragma unroll
    for (int p = 0; p < 2; ++p){
      const int cc = tid + p * 256;
      const int key = cc >> 3, ci = cc & 7;
      const unsigned short* src = k + (size_t)(b * 1024 + ck0 + key) * HDIM + h * 64 + ci * 8;
      GLDS(src, (char*)K_s + p * 4096 + w * 1024);
    }
    // ---- stage V transposed: V_t[dd][key] ----
    {
      ushort4 rr[4];
      #pragma unroll
      for (int kk = 0; kk < 4; ++kk)
        rr[kk] = *(const ushort4*)&v[(size_t)(b * 1024 + ck0 + key0 + kk) * HDIM + h * 64 + dd0];
      #pragma unroll
      for (int cdd = 0; cdd < 4; ++cdd){
        ushort4 wv;
        wv.x = ((const unsigned short*)&rr[0])[cdd];
        wv.y = ((const unsigned short*)&rr[1])[cdd];
        wv.z = ((const unsigned short*)&rr[2])[cdd];
        wv.w = ((const unsigned short*)&rr[3])[cdd];
        *(ushort4*)&V_t[(dd0 + cdd) * 72 + key0] = wv;
      }
    }
    if (tid < 64) act_s[tid] = act[(size_t)b * 1024 + ck0 + tid];
    __syncthreads();

    // ---- S^T = K . Q^T ----
    f32x4 s[4];
    #pragma unroll
    for (int mt = 0; mt < 4; ++mt){ f32x4 z = {0.f,0.f,0.f,0.f}; s[mt] = z; }
    #pragma unroll
    for (int kd = 0; kd < 2; ++kd){
      #pragma unroll
      for (int mt = 0; mt < 4; ++mt){
        const int row = mt * 16 + (lane & 15);
        const bf16x8s kf = *(const bf16x8s*)((const char*)K_s + row * 128 + (kd * 4 + g) * 16);
        s[mt] = __builtin_amdgcn_mfma_f32_16x16x32_bf16(kf, qa[kd], s[mt], 0, 0, 0);
      }
    }

    // ---- mask + online softmax (per-lane q = lane&15; keys on g*4+r) ----
    float sval[4][4];
    float rm = -3.0e38f;
    #pragma unroll
    for (int mt = 0; mt < 4; ++mt){
      const f32x4 av = *(const f32x4*)&act_s[mt * 16 + g * 4];
      #pragma unroll
      for (int r = 0; r < 4; ++r){
        const int key = ck0 + mt * 16 + g * 4 + r;
        float x = fmaf(1.0f - av[r], NEGF, s[mt][r] * 0.125f);
        if (key > qglob) x = -2.0e9f;
        sval[mt][r] = x;
        rm = fmaxf(rm, x);
      }
    }
    rm = fmaxf(rm, __shfl_xor(rm, 16));
    rm = fmaxf(rm, __shfl_xor(rm, 32));
    const float mn = fmaxf(m_r, rm);
    const float sc = expf(m_r - mn);
    float psum = 0.f;
    u32x2 pa[4];
    #pragma unroll
    for (int mt = 0; mt < 4; ++mt){
      float p0 = expf(sval[mt][0] - mn), p1 = expf(sval[mt][1] - mn);
      float p2 = expf(sval[mt][2] - mn), p3 = expf(sval[mt][3] - mn);
      psum += (p0 + p1) + (p2 + p3);
      u32x2 pw;
      pw[0] = (unsigned)f2bf(p0) | ((unsigned)f2bf(p1) << 16);
      pw[1] = (unsigned)f2bf(p2) | ((unsigned)f2bf(p3) << 16);
      pa[mt] = pw;
    }
    psum += __shfl_xor(psum, 16);
    psum += __shfl_xor(psum, 32);
    l_r = l_r * sc + psum;
    m_r = mn;

    // ---- rescale O (O rows are q = 4g + r) ----
    float scq[4];
    #pragma unroll
    for (int r = 0; r < 4; ++r) scq[r] = __shfl(sc, (g << 2) | r);
    #pragma unroll
    for (int n = 0; n < 4; ++n)
      #pragma unroll
      for (int r = 0; r < 4; ++r) oacc[n][r] *= scq[r];

    // ---- PV: O += P.V via 16x16x32 MFMA (K=32 keys per half) ----
    // A-frag (P): lane needs keys half*32 + g*8 + j, j=0..7 (4 u32 words).
    // word t lives on lane (lane&15) + 16*(2*(g&1)+(t>>1)) in pa[2*half + (g>>1)][t&1].
    #pragma unroll
    for (int half = 0; half < 2; ++half){
      unsigned aw[4];
      #pragma unroll
      for (int t = 0; t < 4; ++t){
        const int idx = (lane & 15) + 16 * (2 * (g & 1) + (t >> 1));
        const unsigned wa = __shfl(pa[2 * half][t & 1], idx);
        const unsigned wb = __shfl(pa[2 * half + 1][t & 1], idx);
        aw[t] = (g < 2) ? wa : wb;
      }
      u32x4 av4 = {aw[0], aw[1], aw[2], aw[3]};
      const bf16x8s pfrag = __builtin_bit_cast(bf16x8s, av4);
      #pragma unroll
      for (int n = 0; n < 4; ++n){
        const bf16x8s vfrag = *(const bf16x8s*)&V_t[(n * 16 + (lane & 15)) * 72 + half * 32 + g * 8];
        oacc[n] = __builtin_amdgcn_mfma_f32_16x16x32_bf16(pfrag, vfrag, oacc[n], 0, 0, 0);
      }
    }
    __syncthreads();
  }

  // ---- write O ----
  const float invl = 1.0f / l_r;
  float invq[4];
  #pragma unroll
  for (int r = 0; r < 4; ++r) invq[r] = __shfl(invl, (g << 2) | r);
  #pragma unroll
  for (int n = 0; n < 4; ++n){
    #pragma unroll
    for (int r = 0; r < 4; ++r){
      const size_t addr = (size_t)(b * 1024 + qw + 4 * g + r) * HDIM + h * 64 + n * 16 + (lane & 15);
      o[addr] = f2bf(oacc[n][r] * invq[r]);
    }
  }
}

extern "C" void kernel_launch(void* const* d_in, const int* in_sizes, int n_in,
                              void* d_out, int out_size, void* d_ws, size_t ws_size,
                              hipStream_t stream)
{
  (void)in_sizes; (void)n_in; (void)out_size;
  const float* hidden = (const float*)d_in[0];
  const int*   posids = (const int*)d_in[2];
  const float* ek     = (const float*)d_in[3];
  const float* Wq  = (const float*)d_in[4];
  const float* Wk  = (const float*)d_in[5];
  const float* Wv  = (const float*)d_in[6];
  const float* Wo  = (const float*)d_in[7];
  const float* Wg  = (const float*)d_in[8];
  const float* Wu  = (const float*)d_in[9];
  const float* Wd  = (const float*)d_in[10];
  const float* ln1 = (const float*)d_in[11];
  const float* ln2 = (const float*)d_in[12];
  float* out = (float*)d_out;

  // workspace layout
  unsigned short* Wb = (unsigned short*)d_ws;            // 32M bf16 = 64MB
  float* wX = (float*)(Wb + 33554432);                   // 16MB
  float* wR = wX + 4194304;                              // 16MB
  unsigned short* bA = (unsigned short*)(wR + 4194304);  // hn/h2, 8MB
  unsigned short* bB = bA + 4194304;                     // q / (g|P part)
  unsigned short* bC = bB + 4194304;                     // k
  unsigned short* bD = bC + 4194304;                     // v
  unsigned short* bE = bD + 4194304;                     // o
  unsigned short* bG = bB;                               // g/P: 32MB spans bB..bE
  float* act0 = (float*)(bE + 4194304);
  float* act1 = act0 + BSZ;
  float* g0   = act1 + BSZ;
  float* g1   = g0 + BSZ;
  const size_t needed = (size_t)((char*)(g1 + BSZ) - (char*)d_ws);
  if (ws_size < needed) return;

  // one-time per launch: transpose+convert weights to bf16 [N][K]
  for (int d = 0; d < 2; ++d){
    unsigned short* wt = Wb + (size_t)d * 16777216;
    wtr_kernel<<<dim3(16, 16), 256, 0, stream>>>(Wq + (size_t)d*1048576, wt,            1024, 1024);
    wtr_kernel<<<dim3(16, 16), 256, 0, stream>>>(Wk + (size_t)d*1048576, wt + 1048576,  1024, 1024);
    wtr_kernel<<<dim3(16, 16), 256, 0, stream>>>(Wv + (size_t)d*1048576, wt + 2097152,  1024, 1024);
    wtr_kernel<<<dim3(16, 16), 256, 0, stream>>>(Wo + (size_t)d*1048576, wt + 3145728,  1024, 1024);
    wtr_kernel<<<dim3(64, 16), 256, 0, stream>>>(Wg + (size_t)d*4194304, wt + 4194304,  1024, 4096);
    wtr_kernel<<<dim3(64, 16), 256, 0, stream>>>(Wu + (size_t)d*4194304, wt + 8388608,  1024, 4096);
    wtr_kernel<<<dim3(16, 64), 256, 0, stream>>>(Wd + (size_t)d*4194304, wt + 12582912, 4096, 1024);
  }

  router_kernel<<<BSZ / 4, 256, 0, stream>>>(hidden, ek, out, act0, act1, g0, g1);

  for (int d = 0; d < 2; ++d){
    const float* act  = d ? act1 : act0;
    const float* gate = d ? g1 : g0;
    const float* ekrow = ek + (size_t)(1 << d) * HDIM;
    unsigned short* wt = Wb + (size_t)d * 16777216;
    const unsigned short* wtq = wt;
    const unsigned short* wtk = wt + 1048576;
    const unsigned short* wtv = wt + 2097152;
    const unsigned short* wto = wt + 3145728;
    const unsigned short* wtg = wt + 4194304;
    const unsigned short* wtu = wt + 8388608;
    const unsigned short* wtd = wt + 12582912;

    rms_kernel<true><<<BSZ, 256, 0, stream>>>(out, ekrow, act, ln1 + (size_t)d * HDIM, wX, bA);
    gemm_bf16<0><<<dim3(8, 32), 256, 0, stream>>>(bA, wtq, 1024, 1024, bB, nullptr, nullptr, nullptr, nullptr);
    gemm_bf16<0><<<dim3(8, 32), 256, 0, stream>>>(bA, wtk, 1024, 1024, bC, nullptr, nullptr, nullptr, nullptr);
    gemm_bf16<0><<<dim3(8, 32), 256, 0, stream>>>(bA, wtv, 1024, 1024, bD, nullptr, nullptr, nullptr, nullptr);
    rope_bf16<<<BSZ * 16 / 8, 256, 0, stream>>>(bB, posids);
    rope_bf16<<<BSZ * 16 / 8, 256, 0, stream>>>(bC, posids);
    attn_mfma<<<dim3(16, 16, 4), 256, 0, stream>>>(bB, bC, bD, act, bE);
    gemm_bf16<1><<<dim3(8, 32), 256, 0, stream>>>(bE, wto, 1024, 1024, nullptr, wR, wX, nullptr, nullptr);
    rms_kernel<false><<<BSZ, 256, 0, stream>>>(wR, nullptr, nullptr, ln2 + (size_t)d * HDIM, nullptr, bA);
    gemm_bf16<0><<<dim3(32, 32), 256, 0, stream>>>(bA, wtg, 4096, 1024, bG, nullptr, nullptr, nullptr, nullptr);
    gemm_bf16<2><<<dim3(32, 32), 256, 0, stream>>>(bA, wtu, 4096, 1024, bG, nullptr, nullptr, nullptr, nullptr);
    gemm_bf16<3><<<dim3(8, 32), 256, 0, stream>>>(bG, wtd, 1024, 4096, nullptr, nullptr, wR, gate, out);
  }
}

// Round 5
// 864.758 us; speedup vs baseline: 7.3338x; 1.0929x over previous
//
#include <hip/hip_runtime.h>
#include <math.h>

#define BSZ 4096        // B*S
#define HDIM 1024
#define IDIM 4096
#define QKVN 3072
#define NEGF (-1000000000.0f)

typedef __attribute__((ext_vector_type(8))) short bf16x8s;   // 8 bf16 in 4 VGPR
typedef __attribute__((ext_vector_type(4))) float f32x4;
typedef __attribute__((ext_vector_type(2))) unsigned int u32x2;
typedef __attribute__((ext_vector_type(4))) unsigned int u32x4;

#define GLDS(src, dst) __builtin_amdgcn_global_load_lds( \
    (const __attribute__((address_space(1))) void*)(src), \
    (__attribute__((address_space(3))) void*)(dst), 16, 0, 0)

__device__ inline unsigned short f2bf(float f){
  __bf16 h = (__bf16)f;
  return __builtin_bit_cast(unsigned short, h);
}
__device__ inline float bf2f(unsigned short u){
  unsigned x = ((unsigned)u) << 16;
  return __builtin_bit_cast(float, x);
}

__device__ inline float wredSum(float v){
  #pragma unroll
  for (int off = 32; off; off >>= 1) v += __shfl_xor(v, off);
  return v;
}

// ---------------- router ---------------------------------------------------------
__global__ __launch_bounds__(256) void router_kernel(
    const float* __restrict__ hidden, const float* __restrict__ ek,
    float* __restrict__ out, float* __restrict__ act0, float* __restrict__ act1,
    float* __restrict__ g0, float* __restrict__ g1)
{
  const int lane = threadIdx.x & 63, wid = threadIdx.x >> 6;
  const int row = blockIdx.x * 4 + wid;
  const float* hr = hidden + (size_t)row * HDIM;
  float4 xv[4];
  float s0 = 0.f, s1 = 0.f, s2 = 0.f, s3 = 0.f;
  #pragma unroll
  for (int tt = 0; tt < 4; ++tt){
    const int o = tt * 256 + lane * 4;
    xv[tt] = *(const float4*)&hr[o];
    const float4 e0 = *(const float4*)&ek[0 * HDIM + o];
    const float4 e1 = *(const float4*)&ek[1 * HDIM + o];
    const float4 e2 = *(const float4*)&ek[2 * HDIM + o];
    const float4 e3 = *(const float4*)&ek[3 * HDIM + o];
    s0 += xv[tt].x * e0.x + xv[tt].y * e0.y + xv[tt].z * e0.z + xv[tt].w * e0.w;
    s1 += xv[tt].x * e1.x + xv[tt].y * e1.y + xv[tt].z * e1.z + xv[tt].w * e1.w;
    s2 += xv[tt].x * e2.x + xv[tt].y * e2.y + xv[tt].z * e2.z + xv[tt].w * e2.w;
    s3 += xv[tt].x * e3.x + xv[tt].y * e3.y + xv[tt].z * e3.z + xv[tt].w * e3.w;
  }
  s0 = wredSum(s0); s1 = wredSum(s1); s2 = wredSum(s2); s3 = wredSum(s3);
  int ch = 0; float mx = s0;
  if (s1 > mx){ mx = s1; ch = 1; }
  if (s2 > mx){ mx = s2; ch = 2; }
  if (s3 > mx){ mx = s3; ch = 3; }
  const float den = expf(s0 - mx) + expf(s1 - mx) + expf(s2 - mx) + expf(s3 - mx);
  const float wsel = 1.0f / den;
  if (lane == 0){
    const float a0 = (float)(ch & 1), a1 = (float)((ch >> 1) & 1);
    act0[row] = a0; act1[row] = a1; g0[row] = a0 * wsel; g1[row] = a1 * wsel;
  }
  float* orow = out + (size_t)row * HDIM;
  #pragma unroll
  for (int tt = 0; tt < 4; ++tt) *(float4*)&orow[tt * 256 + lane * 4] = xv[tt];
}

// ---------------- weight transpose+convert: fp32 [K][N] -> bf16 [N][K] -----------
__global__ __launch_bounds__(256) void wtr_kernel(
    const float* __restrict__ src, unsigned short* __restrict__ dst, int K, int N)
{
  __shared__ float T[64][65];
  const int tid = threadIdx.x;
  const int k0 = blockIdx.y * 64, n0 = blockIdx.x * 64;
  const int tx = tid & 15, ty = tid >> 4;
  #pragma unroll
  for (int i = 0; i < 4; ++i){
    const float4 v = *(const float4*)&src[(size_t)(k0 + ty + i*16) * N + n0 + tx*4];
    T[ty + i*16][tx*4 + 0] = v.x;
    T[ty + i*16][tx*4 + 1] = v.y;
    T[ty + i*16][tx*4 + 2] = v.z;
    T[ty + i*16][tx*4 + 3] = v.w;
  }
  __syncthreads();
  #pragma unroll
  for (int i = 0; i < 4; ++i){
    ushort4 u;
    u.x = f2bf(T[tx*4 + 0][ty + i*16]);
    u.y = f2bf(T[tx*4 + 1][ty + i*16]);
    u.z = f2bf(T[tx*4 + 2][ty + i*16]);
    u.w = f2bf(T[tx*4 + 3][ty + i*16]);
    *(ushort4*)&dst[(size_t)(n0 + ty + i*16) * K + k0 + tx*4] = u;
  }
}

// ---------------- rmsnorm ---------------------------------------------------------
template<bool ADD_EK>
__global__ __launch_bounds__(256) void rms_kernel(
    const float* __restrict__ src, const float* __restrict__ ekrow,
    const float* __restrict__ act, const float* __restrict__ g,
    float* __restrict__ xout, unsigned short* __restrict__ hn)
{
  const int row = blockIdx.x;
  const int t = threadIdx.x;
  const int lane = t & 63, wid = t >> 6;
  const float* sr = src + (size_t)row * HDIM;
  float4 xv = *(const float4*)&sr[t * 4];
  if constexpr (ADD_EK){
    const float a = act[row];
    const float4 e = *(const float4*)&ekrow[t * 4];
    xv.x = fmaf(a, e.x, xv.x); xv.y = fmaf(a, e.y, xv.y);
    xv.z = fmaf(a, e.z, xv.z); xv.w = fmaf(a, e.w, xv.w);
  }
  float ss = xv.x*xv.x + xv.y*xv.y + xv.z*xv.z + xv.w*xv.w;
  ss = wredSum(ss);
  __shared__ float red[4];
  if (lane == 0) red[wid] = ss;
  __syncthreads();
  const float tot = red[0] + red[1] + red[2] + red[3];
  const float inv = rsqrtf(tot * (1.0f / HDIM) + 1e-6f);
  if constexpr (ADD_EK) *(float4*)&xout[(size_t)row * HDIM + t * 4] = xv;
  const float4 gg = *(const float4*)&g[t * 4];
  ushort4 hu;
  hu.x = f2bf(xv.x * inv * gg.x); hu.y = f2bf(xv.y * inv * gg.y);
  hu.z = f2bf(xv.z * inv * gg.z); hu.w = f2bf(xv.w * inv * gg.w);
  *(ushort4*)&hn[(size_t)row * HDIM + t * 4] = hu;
}

// ---------------- RoPE in-place on bf16 qkv (q heads 0-15, k heads 16-31) --------
__global__ __launch_bounds__(256) void rope_qk(
    unsigned short* __restrict__ qk, const int* __restrict__ pos_ids)
{
  const int t = threadIdx.x;
  const int u = blockIdx.x * 8 + (t >> 5);
  const int j = t & 31;
  const int row = u >> 5;
  const int head = u & 31;
  const float pos = (float)pos_ids[row];
  const float inv = powf(10000.0f, -(float)j * (1.0f / 32.0f));
  float sn, cs;
  sincosf(pos * inv, &sn, &cs);
  unsigned short* p = qk + (size_t)row * QKVN + head * 64;
  const float a = bf2f(p[j]), b = bf2f(p[j + 32]);
  p[j]      = f2bf(a * cs - b * sn);
  p[j + 32] = f2bf(b * cs + a * sn);
}

// swizzle helpers: LDS[row][slot16B] holds global slot (slot ^ fsw(row))
__device__ inline int fsw(int row){ return (row >> 1) & 3; }

// ---------------- bf16 MFMA GEMM, 128x128 tile, swizzled LDS, XCD remap ----------
// EPI 0: Cb = bf16(acc)
// EPI 1: Cf = res + acc
// EPI 3: outp += gate[row] * (res + acc)
template<int EPI>
__global__ __launch_bounds__(256) void gemm_bf16(
    const unsigned short* __restrict__ A, const unsigned short* __restrict__ Bt,
    int N, int K,
    unsigned short* __restrict__ Cb, float* __restrict__ Cf,
    const float* __restrict__ res, const float* __restrict__ gate,
    float* __restrict__ outp)
{
  __shared__ __align__(16) unsigned short As[8192];   // 2 bufs x 128x32
  __shared__ __align__(16) unsigned short Bs[8192];
  const int tid = threadIdx.x;
  const int lane = tid & 63, w = tid >> 6;
  const int g = lane >> 4;
  // XCD-aware bijective remap (grid sizes are multiples of 8)
  const int nwg = gridDim.x * gridDim.y;
  int bid = blockIdx.y * gridDim.x + blockIdx.x;
  bid = (bid & 7) * (nwg >> 3) + (bid >> 3);
  const int bm = (bid / gridDim.x) * 128, bn = (bid % gridDim.x) * 128;
  const int wr = w >> 1, wc = w & 1;

  const int rA0 = tid >> 2, rA1 = rA0 + 64;
  const int c0 = tid & 3;
  const int sc0 = (c0 ^ fsw(rA0)) * 8;
  const int sc1 = (c0 ^ fsw(rA1)) * 8;
  const unsigned short* gA0 = A  + (size_t)(bm + rA0) * K + sc0;
  const unsigned short* gA1 = A  + (size_t)(bm + rA1) * K + sc1;
  const unsigned short* gB0 = Bt + (size_t)(bn + rA0) * K + sc0;
  const unsigned short* gB1 = Bt + (size_t)(bn + rA1) * K + sc1;
  char* ldsA = (char*)As + w * 1024;
  char* ldsB = (char*)Bs + w * 1024;

  int aoff[4], boff[4];
  #pragma unroll
  for (int i = 0; i < 4; ++i){
    const int ra = wr*64 + i*16 + (lane & 15);
    aoff[i] = ra*64 + ((g ^ fsw(ra)) * 16);
    const int rb = wc*64 + i*16 + (lane & 15);
    boff[i] = rb*64 + ((g ^ fsw(rb)) * 16);
  }

  f32x4 acc[4][4];
  #pragma unroll
  for (int i = 0; i < 4; ++i)
    #pragma unroll
    for (int j = 0; j < 4; ++j){ f32x4 z = {0.f,0.f,0.f,0.f}; acc[i][j] = z; }

  GLDS(gA0, ldsA);        GLDS(gA1, ldsA + 4096);
  GLDS(gB0, ldsB);        GLDS(gB1, ldsB + 4096);
  gA0 += 32; gA1 += 32; gB0 += 32; gB1 += 32;
  __syncthreads();

  const int nk = K >> 5;
  for (int kt = 0; kt < nk; ++kt){
    const int cur = kt & 1;
    if (kt + 1 < nk){
      char* dA = ldsA + ((cur ^ 1) ? 8192 : 0);
      char* dB = ldsB + ((cur ^ 1) ? 8192 : 0);
      GLDS(gA0, dA); GLDS(gA1, dA + 4096);
      GLDS(gB0, dB); GLDS(gB1, dB + 4096);
      gA0 += 32; gA1 += 32; gB0 += 32; gB1 += 32;
    }
    const char* ta = (const char*)As + cur * 8192;
    const char* tb = (const char*)Bs + cur * 8192;
    bf16x8s af[4], bfr[4];
    #pragma unroll
    for (int i = 0; i < 4; ++i){
      af[i]  = *(const bf16x8s*)(ta + aoff[i]);
      bfr[i] = *(const bf16x8s*)(tb + boff[i]);
    }
    #pragma unroll
    for (int i = 0; i < 4; ++i)
      #pragma unroll
      for (int j = 0; j < 4; ++j)
        acc[i][j] = __builtin_amdgcn_mfma_f32_16x16x32_bf16(af[i], bfr[j], acc[i][j], 0, 0, 0);
    __syncthreads();
  }

  const int colb = bn + wc*64 + (lane & 15);
  const int rowb = bm + wr*64 + g*4;
  #pragma unroll
  for (int i = 0; i < 4; ++i){
    #pragma unroll
    for (int j = 0; j < 4; ++j){
      #pragma unroll
      for (int r = 0; r < 4; ++r){
        const int gr = rowb + i*16 + r;
        const int gc = colb + j*16;
        const size_t idx = (size_t)gr * N + gc;
        const float vacc = acc[i][j][r];
        if constexpr (EPI == 0){
          Cb[idx] = f2bf(vacc);
        } else if constexpr (EPI == 1){
          Cf[idx] = res[idx] + vacc;
        } else {
          outp[idx] += gate[gr] * (res[idx] + vacc);
        }
      }
    }
  }
}

// ---------------- fused gate-up GEMM: P = bf16( silu(A@Gt^T) * (A@Ut^T) ) --------
__global__ __launch_bounds__(256) void gemm_gu_bf16(
    const unsigned short* __restrict__ A, const unsigned short* __restrict__ Gt,
    const unsigned short* __restrict__ Ut, int N, int K,
    unsigned short* __restrict__ P)
{
  __shared__ __align__(16) unsigned short As[8192];
  __shared__ __align__(16) unsigned short Gs[8192];
  __shared__ __align__(16) unsigned short Us[8192];
  const int tid = threadIdx.x;
  const int lane = tid & 63, w = tid >> 6;
  const int g = lane >> 4;
  const int nwg = gridDim.x * gridDim.y;
  int bid = blockIdx.y * gridDim.x + blockIdx.x;
  bid = (bid & 7) * (nwg >> 3) + (bid >> 3);
  const int bm = (bid / gridDim.x) * 128, bn = (bid % gridDim.x) * 128;
  const int wr = w >> 1, wc = w & 1;

  const int rA0 = tid >> 2, rA1 = rA0 + 64;
  const int c0 = tid & 3;
  const int sc0 = (c0 ^ fsw(rA0)) * 8;
  const int sc1 = (c0 ^ fsw(rA1)) * 8;
  const unsigned short* gA0 = A  + (size_t)(bm + rA0) * K + sc0;
  const unsigned short* gA1 = A  + (size_t)(bm + rA1) * K + sc1;
  const unsigned short* gG0 = Gt + (size_t)(bn + rA0) * K + sc0;
  const unsigned short* gG1 = Gt + (size_t)(bn + rA1) * K + sc1;
  const unsigned short* gU0 = Ut + (size_t)(bn + rA0) * K + sc0;
  const unsigned short* gU1 = Ut + (size_t)(bn + rA1) * K + sc1;
  char* ldsA = (char*)As + w * 1024;
  char* ldsG = (char*)Gs + w * 1024;
  char* ldsU = (char*)Us + w * 1024;

  int aoff[4], boff[4];
  #pragma unroll
  for (int i = 0; i < 4; ++i){
    const int ra = wr*64 + i*16 + (lane & 15);
    aoff[i] = ra*64 + ((g ^ fsw(ra)) * 16);
    const int rb = wc*64 + i*16 + (lane & 15);
    boff[i] = rb*64 + ((g ^ fsw(rb)) * 16);
  }

  f32x4 accG[4][4], accU[4][4];
  #pragma unroll
  for (int i = 0; i < 4; ++i)
    #pragma unroll
    for (int j = 0; j < 4; ++j){
      f32x4 z = {0.f,0.f,0.f,0.f}; accG[i][j] = z; accU[i][j] = z;
    }

  GLDS(gA0, ldsA); GLDS(gA1, ldsA + 4096);
  GLDS(gG0, ldsG); GLDS(gG1, ldsG + 4096);
  GLDS(gU0, ldsU); GLDS(gU1, ldsU + 4096);
  gA0 += 32; gA1 += 32; gG0 += 32; gG1 += 32; gU0 += 32; gU1 += 32;
  __syncthreads();

  const int nk = K >> 5;
  for (int kt = 0; kt < nk; ++kt){
    const int cur = kt & 1;
    if (kt + 1 < nk){
      const int nxt = (cur ^ 1) ? 8192 : 0;
      GLDS(gA0, ldsA + nxt); GLDS(gA1, ldsA + nxt + 4096);
      GLDS(gG0, ldsG + nxt); GLDS(gG1, ldsG + nxt + 4096);
      GLDS(gU0, ldsU + nxt); GLDS(gU1, ldsU + nxt + 4096);
      gA0 += 32; gA1 += 32; gG0 += 32; gG1 += 32; gU0 += 32; gU1 += 32;
    }
    const char* ta = (const char*)As + cur * 8192;
    const char* tg = (const char*)Gs + cur * 8192;
    const char* tu = (const char*)Us + cur * 8192;
    bf16x8s af[4], gf[4], uf[4];
    #pragma unroll
    for (int i = 0; i < 4; ++i){
      af[i] = *(const bf16x8s*)(ta + aoff[i]);
      gf[i] = *(const bf16x8s*)(tg + boff[i]);
      uf[i] = *(const bf16x8s*)(tu + boff[i]);
    }
    #pragma unroll
    for (int i = 0; i < 4; ++i)
      #pragma unroll
      for (int j = 0; j < 4; ++j){
        accG[i][j] = __builtin_amdgcn_mfma_f32_16x16x32_bf16(af[i], gf[j], accG[i][j], 0, 0, 0);
        accU[i][j] = __builtin_amdgcn_mfma_f32_16x16x32_bf16(af[i], uf[j], accU[i][j], 0, 0, 0);
      }
    __syncthreads();
  }

  const int colb = bn + wc*64 + (lane & 15);
  const int rowb = bm + wr*64 + g*4;
  #pragma unroll
  for (int i = 0; i < 4; ++i){
    #pragma unroll
    for (int j = 0; j < 4; ++j){
      #pragma unroll
      for (int r = 0; r < 4; ++r){
        const size_t idx = (size_t)(rowb + i*16 + r) * N + colb + j*16;
        const float gv = accG[i][j][r];
        const float s = gv / (1.0f + expf(-gv));
        P[idx] = f2bf(s * accU[i][j][r]);
      }
    }
  }
}

// ---------------- MFMA flash attention (16x16x32 only, swizzled K tile) ----------
__global__ __launch_bounds__(256) void attn_mfma(
    const unsigned short* __restrict__ q, const unsigned short* __restrict__ k,
    const unsigned short* __restrict__ v, const float* __restrict__ act,
    unsigned short* __restrict__ o, int LD)
{
  __shared__ __align__(16) unsigned short K_s[4096];      // [64 key][64 d] swizzled
  __shared__ __align__(16) unsigned short V_t[64 * 72];   // [64 dd][72 key-pad]
  __shared__ float act_s[64];
  const int tid = threadIdx.x;
  const int lane = tid & 63, w = tid >> 6;
  const int g = lane >> 4;
  const int b = blockIdx.z, h = blockIdx.y, qt = blockIdx.x;
  const int qw = qt * 64 + w * 16;
  const int qglob = qw + (lane & 15);

  bf16x8s qa[2];
  {
    const size_t qrow = (size_t)(b * 1024 + qglob) * LD + h * 64;
    qa[0] = *(const bf16x8s*)&q[qrow + g * 8];
    qa[1] = *(const bf16x8s*)&q[qrow + 32 + g * 8];
  }

  f32x4 oacc[4];
  #pragma unroll
  for (int n = 0; n < 4; ++n){ f32x4 z = {0.f,0.f,0.f,0.f}; oacc[n] = z; }
  float m_r = -3.0e38f, l_r = 0.f;

  const int key0 = (tid >> 4) * 4;
  const int dd0  = (tid & 15) * 4;
  const int nch = qt + 1;

  for (int c = 0; c < nch; ++c){
    const int ck0 = c * 64;
    // ---- stage K swizzled: K_s[key][ci] = Kg[key][ci ^ (key&7)] ----
    #pragma unroll
    for (int p = 0; p < 2; ++p){
      const int cc = tid + p * 256;
      const int key = cc >> 3, ci = cc & 7;
      const int sci = (ci ^ (key & 7)) * 8;
      const unsigned short* src = k + (size_t)(b * 1024 + ck0 + key) * LD + h * 64 + sci;
      GLDS(src, (char*)K_s + p * 4096 + w * 1024);
    }
    // ---- stage V transposed: V_t[dd][key] ----
    {
      ushort4 rr[4];
      #pragma unroll
      for (int kk = 0; kk < 4; ++kk)
        rr[kk] = *(const ushort4*)&v[(size_t)(b * 1024 + ck0 + key0 + kk) * LD + h * 64 + dd0];
      #pragma unroll
      for (int cdd = 0; cdd < 4; ++cdd){
        ushort4 wv;
        wv.x = ((const unsigned short*)&rr[0])[cdd];
        wv.y = ((const unsigned short*)&rr[1])[cdd];
        wv.z = ((const unsigned short*)&rr[2])[cdd];
        wv.w = ((const unsigned short*)&rr[3])[cdd];
        *(ushort4*)&V_t[(dd0 + cdd) * 72 + key0] = wv;
      }
    }
    if (tid < 64) act_s[tid] = act[(size_t)b * 1024 + ck0 + tid];
    __syncthreads();

    // ---- S^T = K . Q^T ----
    f32x4 s[4];
    #pragma unroll
    for (int mt = 0; mt < 4; ++mt){ f32x4 z = {0.f,0.f,0.f,0.f}; s[mt] = z; }
    #pragma unroll
    for (int kd = 0; kd < 2; ++kd){
      #pragma unroll
      for (int mt = 0; mt < 4; ++mt){
        const int row = mt * 16 + (lane & 15);
        const int slot = (kd * 4 + g) ^ (row & 7);
        const bf16x8s kf = *(const bf16x8s*)((const char*)K_s + row * 128 + slot * 16);
        s[mt] = __builtin_amdgcn_mfma_f32_16x16x32_bf16(kf, qa[kd], s[mt], 0, 0, 0);
      }
    }

    // ---- mask + online softmax ----
    float sval[4][4];
    float rm = -3.0e38f;
    #pragma unroll
    for (int mt = 0; mt < 4; ++mt){
      const f32x4 av = *(const f32x4*)&act_s[mt * 16 + g * 4];
      #pragma unroll
      for (int r = 0; r < 4; ++r){
        const int key = ck0 + mt * 16 + g * 4 + r;
        float x = fmaf(1.0f - av[r], NEGF, s[mt][r] * 0.125f);
        if (key > qglob) x = -2.0e9f;
        sval[mt][r] = x;
        rm = fmaxf(rm, x);
      }
    }
    rm = fmaxf(rm, __shfl_xor(rm, 16));
    rm = fmaxf(rm, __shfl_xor(rm, 32));
    const float mn = fmaxf(m_r, rm);
    const float sc = expf(m_r - mn);
    float psum = 0.f;
    u32x2 pa[4];
    #pragma unroll
    for (int mt = 0; mt < 4; ++mt){
      float p0 = expf(sval[mt][0] - mn), p1 = expf(sval[mt][1] - mn);
      float p2 = expf(sval[mt][2] - mn), p3 = expf(sval[mt][3] - mn);
      psum += (p0 + p1) + (p2 + p3);
      u32x2 pw;
      pw[0] = (unsigned)f2bf(p0) | ((unsigned)f2bf(p1) << 16);
      pw[1] = (unsigned)f2bf(p2) | ((unsigned)f2bf(p3) << 16);
      pa[mt] = pw;
    }
    psum += __shfl_xor(psum, 16);
    psum += __shfl_xor(psum, 32);
    l_r = l_r * sc + psum;
    m_r = mn;

    float scq[4];
    #pragma unroll
    for (int r = 0; r < 4; ++r) scq[r] = __shfl(sc, (g << 2) | r);
    #pragma unroll
    for (int n = 0; n < 4; ++n)
      #pragma unroll
      for (int r = 0; r < 4; ++r) oacc[n][r] *= scq[r];

    // ---- PV via shfl-gathered P fragments + 16x16x32 MFMA ----
    #pragma unroll
    for (int half = 0; half < 2; ++half){
      unsigned aw[4];
      #pragma unroll
      for (int t = 0; t < 4; ++t){
        const int idx = (lane & 15) + 16 * (2 * (g & 1) + (t >> 1));
        const unsigned wa = __shfl(pa[2 * half][t & 1], idx);
        const unsigned wb = __shfl(pa[2 * half + 1][t & 1], idx);
        aw[t] = (g < 2) ? wa : wb;
      }
      u32x4 av4 = {aw[0], aw[1], aw[2], aw[3]};
      const bf16x8s pfrag = __builtin_bit_cast(bf16x8s, av4);
      #pragma unroll
      for (int n = 0; n < 4; ++n){
        const bf16x8s vfrag = *(const bf16x8s*)&V_t[(n * 16 + (lane & 15)) * 72 + half * 32 + g * 8];
        oacc[n] = __builtin_amdgcn_mfma_f32_16x16x32_bf16(pfrag, vfrag, oacc[n], 0, 0, 0);
      }
    }
    __syncthreads();
  }

  const float invl = 1.0f / l_r;
  float invq[4];
  #pragma unroll
  for (int r = 0; r < 4; ++r) invq[r] = __shfl(invl, (g << 2) | r);
  #pragma unroll
  for (int n = 0; n < 4; ++n){
    #pragma unroll
    for (int r = 0; r < 4; ++r){
      const size_t addr = (size_t)(b * 1024 + qw + 4 * g + r) * HDIM + h * 64 + n * 16 + (lane & 15);
      o[addr] = f2bf(oacc[n][r] * invq[r]);
    }
  }
}

extern "C" void kernel_launch(void* const* d_in, const int* in_sizes, int n_in,
                              void* d_out, int out_size, void* d_ws, size_t ws_size,
                              hipStream_t stream)
{
  (void)in_sizes; (void)n_in; (void)out_size;
  const float* hidden = (const float*)d_in[0];
  const int*   posids = (const int*)d_in[2];
  const float* ek     = (const float*)d_in[3];
  const float* Wq  = (const float*)d_in[4];
  const float* Wk  = (const float*)d_in[5];
  const float* Wv  = (const float*)d_in[6];
  const float* Wo  = (const float*)d_in[7];
  const float* Wg  = (const float*)d_in[8];
  const float* Wu  = (const float*)d_in[9];
  const float* Wd  = (const float*)d_in[10];
  const float* ln1 = (const float*)d_in[11];
  const float* ln2 = (const float*)d_in[12];
  float* out = (float*)d_out;

  // workspace layout
  unsigned short* Wb = (unsigned short*)d_ws;            // 32M shorts = 64MB
  float* wX = (float*)(Wb + 33554432);                   // 16MB
  float* wR = wX + 4194304;                              // 16MB
  unsigned short* bA   = (unsigned short*)(wR + 4194304);// hn/h2, 8MB
  unsigned short* bQKV = bA + 4194304;                   // 4096x3072, 24MB
  unsigned short* bE   = bQKV + 12582912;                // o, 8MB
  unsigned short* bG   = bQKV;                           // gu product 32MB (aliases bQKV+bE)
  float* act0 = (float*)(bE + 4194304);
  float* act1 = act0 + BSZ;
  float* g0   = act1 + BSZ;
  float* g1   = g0 + BSZ;
  const size_t needed = (size_t)((char*)(g1 + BSZ) - (char*)d_ws);
  if (ws_size < needed) return;

  // one-time per launch: transpose+convert weights to bf16 [N][K]
  for (int d = 0; d < 2; ++d){
    unsigned short* wt = Wb + (size_t)d * 16777216;
    wtr_kernel<<<dim3(16, 16), 256, 0, stream>>>(Wq + (size_t)d*1048576, wt,            1024, 1024);
    wtr_kernel<<<dim3(16, 16), 256, 0, stream>>>(Wk + (size_t)d*1048576, wt + 1048576,  1024, 1024);
    wtr_kernel<<<dim3(16, 16), 256, 0, stream>>>(Wv + (size_t)d*1048576, wt + 2097152,  1024, 1024);
    wtr_kernel<<<dim3(16, 16), 256, 0, stream>>>(Wo + (size_t)d*1048576, wt + 3145728,  1024, 1024);
    wtr_kernel<<<dim3(64, 16), 256, 0, stream>>>(Wg + (size_t)d*4194304, wt + 4194304,  1024, 4096);
    wtr_kernel<<<dim3(64, 16), 256, 0, stream>>>(Wu + (size_t)d*4194304, wt + 8388608,  1024, 4096);
    wtr_kernel<<<dim3(16, 64), 256, 0, stream>>>(Wd + (size_t)d*4194304, wt + 12582912, 4096, 1024);
  }

  router_kernel<<<BSZ / 4, 256, 0, stream>>>(hidden, ek, out, act0, act1, g0, g1);

  for (int d = 0; d < 2; ++d){
    const float* act  = d ? act1 : act0;
    const float* gate = d ? g1 : g0;
    const float* ekrow = ek + (size_t)(1 << d) * HDIM;
    unsigned short* wt = Wb + (size_t)d * 16777216;
    const unsigned short* wtqkv = wt;                 // [3072][1024] (Q|K|V)
    const unsigned short* wto = wt + 3145728;
    const unsigned short* wtg = wt + 4194304;
    const unsigned short* wtu = wt + 8388608;
    const unsigned short* wtd = wt + 12582912;

    rms_kernel<true><<<BSZ, 256, 0, stream>>>(out, ekrow, act, ln1 + (size_t)d * HDIM, wX, bA);
    // fused QKV: C[4096][3072]
    gemm_bf16<0><<<dim3(QKVN / 128, 32), 256, 0, stream>>>(bA, wtqkv, QKVN, 1024, bQKV, nullptr, nullptr, nullptr, nullptr);
    rope_qk<<<BSZ * 32 / 8, 256, 0, stream>>>(bQKV, posids);
    attn_mfma<<<dim3(16, 16, 4), 256, 0, stream>>>(bQKV, bQKV + 1024, bQKV + 2048, act, bE, QKVN);
    gemm_bf16<1><<<dim3(8, 32), 256, 0, stream>>>(bE, wto, 1024, 1024, nullptr, wR, wX, nullptr, nullptr);
    rms_kernel<false><<<BSZ, 256, 0, stream>>>(wR, nullptr, nullptr, ln2 + (size_t)d * HDIM, nullptr, bA);
    gemm_gu_bf16<<<dim3(IDIM / 128, 32), 256, 0, stream>>>(bA, wtg, wtu, IDIM, 1024, bG);
    gemm_bf16<3><<<dim3(8, 32), 256, 0, stream>>>(bG, wtd, 1024, 4096, nullptr, nullptr, wR, gate, out);
  }
}